// Round 1
// baseline (1075.068 us; speedup 1.0000x reference)
//
#include <hip/hip_runtime.h>
#include <math.h>

#define NPTS   512
#define NLIGHT 100
#define NRAY   (NPTS * NLIGHT)   // 51200
#define NS     50
#define NI     30
#define NF     80                // NS + NI
#define HID    256
#define NEAR_  0.1f
#define FAR_   3.0f

// ---------------- Phase A: per-ray coarse pass + importance sampling + fine alphas -------------

struct RayScratch {
  float zv[NS];      // 50 coarse z values
  float ac[NS];      // 50 coarse alphas
  float wgt[NS - 2]; // 48 weights (+1e-5)
  float cdf[NS - 1]; // 49 cdf values (cdf[0]=0)
  float zs[NI];      // 30 importance samples
  float zall[NF];    // 80 merged z values
};

__device__ __forceinline__ float sigma_eval(float x, float y, float z,
                                            const float* __restrict__ wf, float bf0) {
  // embed order: [x,y,z, (sin f*x, sin f*y, sin f*z, cos f*x, cos f*y, cos f*z) for f=1,2,4,8]
  float s = bf0 + wf[0] * x + wf[1] * y + wf[2] * z;
  float f = 1.0f;
#pragma unroll
  for (int k = 0; k < 4; ++k) {
    const float ax = x * f, ay = y * f, az = z * f;
    s += wf[3 + 6 * k + 0] * sinf(ax);
    s += wf[3 + 6 * k + 1] * sinf(ay);
    s += wf[3 + 6 * k + 2] * sinf(az);
    s += wf[3 + 6 * k + 3] * cosf(ax);
    s += wf[3 + 6 * k + 4] * cosf(ay);
    s += wf[3 + 6 * k + 5] * cosf(az);
    f *= 2.0f;
  }
  return s;
}

__global__ __launch_bounds__(256) void phase_a(
    const float* __restrict__ pts, const float* __restrict__ lights,
    const float* __restrict__ sincol, const float* __restrict__ normal,
    const float* __restrict__ rb, const float* __restrict__ wf,
    const float* __restrict__ bf,
    float* __restrict__ alpha_out, float* __restrict__ cosin_out) {
  __shared__ RayScratch sh[4];
  const int wave = threadIdx.x >> 6;
  const int lane = threadIdx.x & 63;
  const int ray  = blockIdx.x * 4 + wave;   // grid sized exactly: NRAY/4 blocks
  const int i = ray / NLIGHT, j = ray % NLIGHT;
  RayScratch& S = sh[wave];

  const float px = pts[3 * i + 0], py = pts[3 * i + 1], pz = pts[3 * i + 2];
  const float dx = lights[3 * j + 0] - px;
  const float dy = lights[3 * j + 1] - py;
  const float dz = lights[3 * j + 2] - pz;
  const float nrm = sqrtf(dx * dx + dy * dy + dz * dz);
  const float rdx = dx / nrm, rdy = dy / nrm, rdz = dz / nrm;
  // reference re-takes the norm of the (already normalized) dirs for fine dists
  const float n2 = sqrtf(rdx * rdx + rdy * rdy + rdz * rdz);
  const float bf0 = bf[0];

  if (lane == 0) {
    const float dotn = rdx * normal[3 * i + 0] + rdy * normal[3 * i + 1] + rdz * normal[3 * i + 2];
    cosin_out[ray] = (dotn > 0.0f) ? 1.0f : 0.0f;
  }

  if (lane < NS) {
    const float t = (float)lane / (float)(NS - 1);
    S.zv[lane] = NEAR_ * (1.0f - t) + FAR_ * t;
  }
  __syncthreads();

  if (lane < NS) {
    const float z = S.zv[lane];
    const float bias = (sincol[j] * z * 0.01f) * (rb[(i * NLIGHT + j) * NS + lane] * 2.0f - 1.0f);
    const float sig = sigma_eval(px + rdx * z + bias, py + rdy * z + bias, pz + rdz * z + bias, wf, bf0);
    const float dist = (lane < NS - 1) ? (S.zv[lane + 1] - z) : 1e10f;
    S.ac[lane] = 1.0f - expf(-fmaxf(sig, 0.0f) * dist);
  }
  __syncthreads();

  if (lane == 0) {
    // transmittance scan + weights[1..48] (+1e-5), then cdf
    float trans = 1.0f, wsum = 0.0f;
    for (int s = 0; s < NS; ++s) {
      const float a = S.ac[s];
      const float w = a * trans;
      trans *= 1.0f - a + 1e-10f;
      if (s >= 1 && s <= NS - 2) {
        const float ww = w + 1e-5f;
        S.wgt[s - 1] = ww;
        wsum += ww;
      }
    }
    float run = 0.0f;
    S.cdf[0] = 0.0f;
    for (int k = 0; k < NS - 2; ++k) {
      run += S.wgt[k] / wsum;
      S.cdf[k + 1] = run;
    }
  }
  __syncthreads();

  if (lane < NI) {
    const float u = (float)lane / (float)(NI - 1);
    // searchsorted(cdf, u, side='right') over 49 entries
    int ind = 0;
#pragma unroll
    for (int k = 0; k < NS - 1; ++k)
      if (S.cdf[k] <= u) ind = k + 1;
    const int below = max(ind - 1, 0);
    const int above = min(ind, NS - 2);
    const float c0 = S.cdf[below], c1 = S.cdf[above];
    const float b0v = 0.5f * (S.zv[below] + S.zv[below + 1]);   // z_mid[below]
    const float b1v = 0.5f * (S.zv[above] + S.zv[above + 1]);   // z_mid[above]
    float den = c1 - c0;
    if (den < 1e-5f) den = 1.0f;
    const float t = (u - c0) / den;
    S.zs[lane] = b0v + t * (b1v - b0v);
  }
  __syncthreads();

  if (lane == 0) {
    // merge two sorted lists (zv 50, zs 30) -> zall 80  (== jnp.sort of concat)
    int a = 0, b = 0;
    for (int k = 0; k < NF; ++k) {
      const float va = (a < NS) ? S.zv[a] : 3.0e38f;
      const float vb = (b < NI) ? S.zs[b] : 3.0e38f;
      if (va <= vb) { S.zall[k] = va; ++a; }
      else          { S.zall[k] = vb; ++b; }
    }
  }
  __syncthreads();

  for (int k = lane; k < NF; k += 64) {
    const float z = S.zall[k];
    const float d = ((k < NF - 1) ? (S.zall[k + 1] - z) : 1e10f) * n2;
    const float sig = sigma_eval(px + rdx * z, py + rdy * z, pz + rdz * z, wf, bf0);
    alpha_out[ray * NF + k] = 1.0f - expf(-fmaxf(sig, 0.0f) * d);
  }
}

// ---------------- Phase B: 8-layer MLP (fp32 baseline) ----------------
// Block = 256 threads = 4 waves; 32 rays/block, 8 rays/wave.
// Each lane owns 4 output neurons (o = 4*lane .. 4*lane+3) and 8 rays -> acc[8][4].
// CAT[r][0..79] = alpha_f (skip input), CAT[r][80..335] = hA. HB[r][0..255] = hB.
// Layer5 input is the contiguous CAT row (concat for free).

#define RPW 8
#define RPB 32
#define CATW 336

template <int DIN>
__device__ __forceinline__ void layer_fw(const float* __restrict__ W, const float* __restrict__ B,
                                         const float* __restrict__ hsrc, int sstr,
                                         float* __restrict__ hdst, int dstr, int lane) {
  float acc[RPW][4];
  const float4 bb = *(const float4*)(B + 4 * lane);
#pragma unroll
  for (int r = 0; r < RPW; ++r) {
    acc[r][0] = bb.x; acc[r][1] = bb.y; acc[r][2] = bb.z; acc[r][3] = bb.w;
  }
  for (int k = 0; k < DIN; k += 4) {
    const float4 w0 = *(const float4*)(W + (k + 0) * HID + 4 * lane);
    const float4 w1 = *(const float4*)(W + (k + 1) * HID + 4 * lane);
    const float4 w2 = *(const float4*)(W + (k + 2) * HID + 4 * lane);
    const float4 w3 = *(const float4*)(W + (k + 3) * HID + 4 * lane);
#pragma unroll
    for (int r = 0; r < RPW; ++r) {
      const float4 h = *(const float4*)(hsrc + r * sstr + k);  // LDS broadcast
      acc[r][0] += h.x * w0.x + h.y * w1.x + h.z * w2.x + h.w * w3.x;
      acc[r][1] += h.x * w0.y + h.y * w1.y + h.z * w2.y + h.w * w3.y;
      acc[r][2] += h.x * w0.z + h.y * w1.z + h.z * w2.z + h.w * w3.z;
      acc[r][3] += h.x * w0.w + h.y * w1.w + h.z * w2.w + h.w * w3.w;
    }
  }
#pragma unroll
  for (int r = 0; r < RPW; ++r) {
    float4 o;
    o.x = fmaxf(acc[r][0], 0.0f);
    o.y = fmaxf(acc[r][1], 0.0f);
    o.z = fmaxf(acc[r][2], 0.0f);
    o.w = fmaxf(acc[r][3], 0.0f);
    *(float4*)(hdst + r * dstr + 4 * lane) = o;
  }
}

__global__ __launch_bounds__(256) void mlp_fw(
    const float* __restrict__ alpha_buf, const float* __restrict__ cosin_buf,
    const float* __restrict__ w0, const float* __restrict__ b0,
    const float* __restrict__ w1, const float* __restrict__ b1,
    const float* __restrict__ w2, const float* __restrict__ b2,
    const float* __restrict__ w3, const float* __restrict__ b3,
    const float* __restrict__ w4, const float* __restrict__ b4,
    const float* __restrict__ w5, const float* __restrict__ b5,
    const float* __restrict__ w6, const float* __restrict__ b6,
    const float* __restrict__ w7, const float* __restrict__ b7,
    const float* __restrict__ wl, const float* __restrict__ bl,
    float* __restrict__ out) {
  __shared__ float CAT[RPB][CATW];
  __shared__ float HB[RPB][HID];
  const int tid = threadIdx.x, wave = tid >> 6, lane = tid & 63;
  const int ray0 = blockIdx.x * RPB;

  for (int idx = tid; idx < RPB * NF; idx += 256) {
    const int r = idx / NF, k = idx % NF;
    CAT[r][k] = alpha_buf[(ray0 + r) * NF + k];
  }
  __syncthreads();

  const int rb_ = wave * RPW;
  const float* cat0 = &CAT[rb_][0];
  float* catA = &CAT[rb_][0] + NF;
  float* hb   = &HB[rb_][0];

  layer_fw<80 >(w0, b0, cat0, CATW, catA, CATW, lane); __syncthreads();
  layer_fw<256>(w1, b1, catA, CATW, hb,   HID,  lane); __syncthreads();
  layer_fw<256>(w2, b2, hb,   HID,  catA, CATW, lane); __syncthreads();
  layer_fw<256>(w3, b3, catA, CATW, hb,   HID,  lane); __syncthreads();
  layer_fw<256>(w4, b4, hb,   HID,  catA, CATW, lane); __syncthreads();
  layer_fw<336>(w5, b5, cat0, CATW, hb,   HID,  lane); __syncthreads();  // skip concat by layout
  layer_fw<256>(w6, b6, hb,   HID,  catA, CATW, lane); __syncthreads();
  layer_fw<256>(w7, b7, catA, CATW, hb,   HID,  lane); __syncthreads();

  const float4 wv = *(const float4*)(wl + 4 * lane);
  const float blv = bl[0];
  for (int r = 0; r < RPW; ++r) {
    const float4 hv = *(const float4*)(hb + r * HID + 4 * lane);
    float p = wv.x * hv.x + wv.y * hv.y + wv.z * hv.z + wv.w * hv.w;
#pragma unroll
    for (int off = 32; off > 0; off >>= 1) p += __shfl_xor(p, off, 64);
    if (lane == 0) {
      const int ray = ray0 + rb_ + r;
      const float v = 1.0f / (1.0f + expf(-(p + blv)));
      out[ray] = v * cosin_buf[ray];
    }
  }
}

// ---------------- launch ----------------

extern "C" void kernel_launch(void* const* d_in, const int* in_sizes, int n_in,
                              void* d_out, int out_size, void* d_ws, size_t ws_size,
                              hipStream_t stream) {
  const float* pts    = (const float*)d_in[0];
  const float* lights = (const float*)d_in[1];
  const float* sincol = (const float*)d_in[2];
  const float* normal = (const float*)d_in[3];
  const float* rb     = (const float*)d_in[4];
  const float* wf     = (const float*)d_in[5];
  const float* bf     = (const float*)d_in[6];
  const float* wlast  = (const float*)d_in[7];
  const float* blast  = (const float*)d_in[8];
  const float* w0 = (const float*)d_in[9];  const float* b0 = (const float*)d_in[10];
  const float* w1 = (const float*)d_in[11]; const float* b1 = (const float*)d_in[12];
  const float* w2 = (const float*)d_in[13]; const float* b2 = (const float*)d_in[14];
  const float* w3 = (const float*)d_in[15]; const float* b3 = (const float*)d_in[16];
  const float* w4 = (const float*)d_in[17]; const float* b4 = (const float*)d_in[18];
  const float* w5 = (const float*)d_in[19]; const float* b5 = (const float*)d_in[20];
  const float* w6 = (const float*)d_in[21]; const float* b6 = (const float*)d_in[22];
  const float* w7 = (const float*)d_in[23]; const float* b7 = (const float*)d_in[24];

  float* alpha_buf = (float*)d_ws;                 // [NRAY][80]
  float* cosin_buf = alpha_buf + (size_t)NRAY * NF; // [NRAY]
  float* out = (float*)d_out;

  phase_a<<<NRAY / 4, 256, 0, stream>>>(pts, lights, sincol, normal, rb, wf, bf,
                                        alpha_buf, cosin_buf);
  mlp_fw<<<NRAY / RPB, 256, 0, stream>>>(alpha_buf, cosin_buf,
                                         w0, b0, w1, b1, w2, b2, w3, b3, w4, b4,
                                         w5, b5, w6, b6, w7, b7, wlast, blast, out);
}

// Round 2
// 266.682 us; speedup vs baseline: 4.0313x; 4.0313x over previous
//
#include <hip/hip_runtime.h>
#include <math.h>

#define NPTS   512
#define NLIGHT 100
#define NRAY   (NPTS * NLIGHT)   // 51200
#define NS     50
#define NI     30
#define NF     80                // NS + NI
#define HID    256
#define NEAR_  0.1f
#define FAR_   3.0f

typedef _Float16 half8 __attribute__((ext_vector_type(8)));
typedef float    f32x4 __attribute__((ext_vector_type(4)));

// ---- packed weight layout (f16 elements), B-fragment major ----
// per layer: idx = ((nf*KST + ks)*64 + lane)*8 + j ; n = nf*16 + (lane&15),
// k = ks*32 + ((lane>>4)&3)*8 + j
#define KP0 96
#define KP5 352
#define OB0 0
#define OB1 (OB0 + KP0*HID)        // 24576
#define OB2 (OB1 + HID*HID)        // 90112
#define OB3 (OB2 + HID*HID)
#define OB4 (OB3 + HID*HID)
#define OB5 (OB4 + HID*HID)
#define OB6 (OB5 + KP5*HID)
#define OB7 (OB6 + HID*HID)
#define WPACK_TOTAL (OB7 + HID*HID)  // 507904 f16

#define ASTRIDE 264                 // 256 + 8 f16 pad (528B row: bank-stagger)

// ================= weight prep: fp32 [K][N] -> packed f16 fragments =================
template <int KST>
__device__ __forceinline__ void decode_kn(int rem, int& n, int& kk) {
  const int j = rem & 7, q = rem >> 3;
  const int lane = q & 63, q2 = q >> 6;
  const int ks = q2 % KST, nf = q2 / KST;
  n  = nf * 16 + (lane & 15);
  kk = ks * 32 + ((lane >> 4) & 3) * 8 + j;
}

__global__ __launch_bounds__(256) void prep_w(
    const float* __restrict__ w0, const float* __restrict__ w1,
    const float* __restrict__ w2, const float* __restrict__ w3,
    const float* __restrict__ w4, const float* __restrict__ w5,
    const float* __restrict__ w6, const float* __restrict__ w7,
    _Float16* __restrict__ wp) {
  const int t = blockIdx.x * 256 + threadIdx.x;
  if (t >= WPACK_TOTAL) return;
  int n, kk;
  float v = 0.0f;
  if (t < OB1)      { decode_kn<3>(t - OB0, n, kk); if (kk < 80) v = w0[kk * HID + n]; }
  else if (t < OB2) { decode_kn<8>(t - OB1, n, kk); v = w1[kk * HID + n]; }
  else if (t < OB3) { decode_kn<8>(t - OB2, n, kk); v = w2[kk * HID + n]; }
  else if (t < OB4) { decode_kn<8>(t - OB3, n, kk); v = w3[kk * HID + n]; }
  else if (t < OB5) { decode_kn<8>(t - OB4, n, kk); v = w4[kk * HID + n]; }
  else if (t < OB6) { decode_kn<11>(t - OB5, n, kk);
                      if (kk < 80) v = w5[kk * HID + n];
                      else if (kk >= 96) v = w5[(kk - 16) * HID + n]; }
  else if (t < OB7) { decode_kn<8>(t - OB6, n, kk); v = w6[kk * HID + n]; }
  else              { decode_kn<8>(t - OB7, n, kk); v = w7[kk * HID + n]; }
  wp[t] = (_Float16)v;
}

// ================= Phase A =================
struct RayScratch {
  float zv[NS];
  float cdf[NS - 1];
  float zs[NI];
  float zall[NF];
  float af[NF];
};

__device__ __forceinline__ float sigma_fast(float x, float y, float z,
                                            const float* __restrict__ wfr, float bf0) {
  float s = bf0 + wfr[0] * x + wfr[1] * y + wfr[2] * z;
  float sx, cx, sy, cy, sz, cz;
  __sincosf(x, &sx, &cx);
  __sincosf(y, &sy, &cy);
  __sincosf(z, &sz, &cz);
#pragma unroll
  for (int k = 0; k < 4; ++k) {
    s += wfr[3 + 6 * k + 0] * sx + wfr[3 + 6 * k + 1] * sy + wfr[3 + 6 * k + 2] * sz;
    s += wfr[3 + 6 * k + 3] * cx + wfr[3 + 6 * k + 4] * cy + wfr[3 + 6 * k + 5] * cz;
    if (k < 3) {
      const float sx2 = 2.0f * sx * cx, cx2 = 1.0f - 2.0f * sx * sx;
      const float sy2 = 2.0f * sy * cy, cy2 = 1.0f - 2.0f * sy * sy;
      const float sz2 = 2.0f * sz * cz, cz2 = 1.0f - 2.0f * sz * sz;
      sx = sx2; cx = cx2; sy = sy2; cy = cy2; sz = sz2; cz = cz2;
    }
  }
  return s;
}

__global__ __launch_bounds__(256) void phase_a(
    const float* __restrict__ pts, const float* __restrict__ lights,
    const float* __restrict__ sincol, const float* __restrict__ normal,
    const float* __restrict__ rb, const float* __restrict__ wf,
    const float* __restrict__ bf,
    _Float16* __restrict__ apack, float* __restrict__ cosin_out) {
  __shared__ RayScratch sh[4];
  const int wave = threadIdx.x >> 6;
  const int lane = threadIdx.x & 63;
  const int ray  = blockIdx.x * 4 + wave;
  const int i = ray / NLIGHT, j = ray % NLIGHT;
  RayScratch& S = sh[wave];

  float wfr[27];
#pragma unroll
  for (int k = 0; k < 27; ++k) wfr[k] = wf[k];
  const float bf0 = bf[0];

  const float px = pts[3 * i + 0], py = pts[3 * i + 1], pz = pts[3 * i + 2];
  const float dx = lights[3 * j + 0] - px;
  const float dy = lights[3 * j + 1] - py;
  const float dz = lights[3 * j + 2] - pz;
  const float nrm = sqrtf(dx * dx + dy * dy + dz * dz);
  const float rdx = dx / nrm, rdy = dy / nrm, rdz = dz / nrm;
  const float n2 = sqrtf(rdx * rdx + rdy * rdy + rdz * rdz);

  if (lane == 0) {
    const float dotn = rdx * normal[3 * i + 0] + rdy * normal[3 * i + 1] + rdz * normal[3 * i + 2];
    cosin_out[ray] = (dotn > 0.0f) ? 1.0f : 0.0f;
  }

  if (lane < NS) {
    const float t = (float)lane / (float)(NS - 1);
    S.zv[lane] = NEAR_ * (1.0f - t) + FAR_ * t;
  }
  __syncthreads();

  // coarse alpha (lane-local)
  float a = 0.0f;
  if (lane < NS) {
    const float z = S.zv[lane];
    const float bias = (sincol[j] * z * 0.01f) * (rb[(i * NLIGHT + j) * NS + lane] * 2.0f - 1.0f);
    const float sig = sigma_fast(px + rdx * z + bias, py + rdy * z + bias, pz + rdz * z + bias, wfr, bf0);
    const float dist = (lane < NS - 1) ? (S.zv[lane + 1] - z) : 1e10f;
    a = 1.0f - __expf(-fmaxf(sig, 0.0f) * dist);
  }

  // parallel exclusive product scan for transmittance
  float v = (lane < NS) ? (1.0f - a + 1e-10f) : 1.0f;
#pragma unroll
  for (int off = 1; off < 64; off <<= 1) {
    const float o = __shfl_up(v, off, 64);
    if (lane >= off) v *= o;
  }
  float trans = __shfl_up(v, 1, 64);
  if (lane == 0) trans = 1.0f;
  const float w = a * trans;
  const float ww = (lane >= 1 && lane <= NS - 2) ? (w + 1e-5f) : 0.0f;
  // wave sum
  float t = ww;
#pragma unroll
  for (int off = 1; off < 64; off <<= 1) t += __shfl_xor(t, off, 64);
  const float pdf = ww / t;
  // inclusive sum scan of pdf -> cdf
  float c = pdf;
#pragma unroll
  for (int off = 1; off < 64; off <<= 1) {
    const float o = __shfl_up(c, off, 64);
    if (lane >= off) c += o;
  }
  if (lane < NS - 1) S.cdf[lane] = c;  // lane0 holds 0
  __syncthreads();

  if (lane < NI) {
    const float u = (float)lane / (float)(NI - 1);
    int ind = 0;
#pragma unroll
    for (int k = 0; k < NS - 1; ++k)
      if (S.cdf[k] <= u) ind = k + 1;
    const int below = max(ind - 1, 0);
    const int above = min(ind, NS - 2);
    const float c0 = S.cdf[below], c1 = S.cdf[above];
    const float b0v = 0.5f * (S.zv[below] + S.zv[below + 1]);
    const float b1v = 0.5f * (S.zv[above] + S.zv[above + 1]);
    float den = c1 - c0;
    if (den < 1e-5f) den = 1.0f;
    S.zs[lane] = b0v + (u - c0) / den * (b1v - b0v);
  }
  __syncthreads();

  // parallel rank merge (stable: zv before zs on ties)
  if (lane < NS) {
    const float zvv = S.zv[lane];
    int cnt = 0;
#pragma unroll
    for (int k = 0; k < NI; ++k) cnt += (S.zs[k] < zvv) ? 1 : 0;
    S.zall[lane + cnt] = zvv;
  }
  __syncthreads();
  if (lane < NI) {
    const float zsv = S.zs[lane];
    int cnt = 0;
#pragma unroll
    for (int k = 0; k < NS; ++k) cnt += (S.zv[k] <= zsv) ? 1 : 0;
    S.zall[lane + cnt] = zsv;
  }
  __syncthreads();

  for (int k = lane; k < NF; k += 64) {
    const float z = S.zall[k];
    const float d = ((k < NF - 1) ? (S.zall[k + 1] - z) : 1e10f) * n2;
    const float sig = sigma_fast(px + rdx * z, py + rdy * z, pz + rdz * z, wfr, bf0);
    S.af[k] = 1.0f - __expf(-fmaxf(sig, 0.0f) * d);
  }
  __syncthreads();

  // pack alpha into A-fragment layout (padded to K=96 with zeros)
  if (lane < 12) {
    const int ks = lane >> 2, kb = lane & 3;
    half8 vv;
#pragma unroll
    for (int jj = 0; jj < 8; ++jj) {
      const int k = ks * 32 + kb * 8 + jj;
      vv[jj] = (_Float16)((k < NF) ? S.af[k] : 0.0f);
    }
    *(half8*)(apack + ((size_t)((ray >> 4) * 3 + ks) * 64 + kb * 16 + (ray & 15)) * 8) = vv;
  }
}

// ================= Phase B: f16 MFMA MLP =================
// block: 256 thr = 4 waves, 128 rays. wave (mt,nt): rays [mt*64,+64), neurons [nt*128,+128).
// acc[4][8] 16x16 fragments. A in LDS f16 [128][ASTRIDE] ping-pong; B from packed global.

__device__ __forceinline__ void init_bias(f32x4 acc[4][8], const float* __restrict__ b,
                                          int lane, int nt) {
#pragma unroll
  for (int ni = 0; ni < 8; ++ni) {
    const float bv = b[nt * 128 + ni * 16 + (lane & 15)];
#pragma unroll
    for (int mi = 0; mi < 4; ++mi) {
      acc[mi][ni][0] = bv; acc[mi][ni][1] = bv; acc[mi][ni][2] = bv; acc[mi][ni][3] = bv;
    }
  }
}

template <int KST, int KS0, int KSN>
__device__ __forceinline__ void gemm_lds(f32x4 acc[4][8], const _Float16* __restrict__ src,
                                         const _Float16* __restrict__ wp, int lane, int mt, int nt) {
#pragma unroll
  for (int ks = KS0; ks < KSN; ++ks) {
    half8 af[4];
    const int kb = (ks - KS0) * 32 + (lane >> 4) * 8;
#pragma unroll
    for (int mi = 0; mi < 4; ++mi) {
      const int row = mt * 64 + mi * 16 + (lane & 15);
      af[mi] = *(const half8*)(src + row * ASTRIDE + kb);
    }
#pragma unroll
    for (int ni = 0; ni < 8; ++ni) {
      const half8 bfr = *(const half8*)(wp + ((size_t)((nt * 8 + ni) * KST + ks) * 64 + lane) * 8);
#pragma unroll
      for (int mi = 0; mi < 4; ++mi)
        acc[mi][ni] = __builtin_amdgcn_mfma_f32_16x16x32_f16(af[mi], bfr, acc[mi][ni], 0, 0, 0);
    }
  }
}

template <int KST, int KS0, int KSN>
__device__ __forceinline__ void gemm_glob(f32x4 acc[4][8], const _Float16* __restrict__ ap,
                                          const _Float16* __restrict__ wp, int lane, int mt, int nt,
                                          int rtb) {
#pragma unroll
  for (int ks = KS0; ks < KSN; ++ks) {
    half8 af[4];
#pragma unroll
    for (int mi = 0; mi < 4; ++mi)
      af[mi] = *(const half8*)(ap + ((size_t)((rtb + mi) * 3 + (ks - KS0)) * 64 + lane) * 8);
#pragma unroll
    for (int ni = 0; ni < 8; ++ni) {
      const half8 bfr = *(const half8*)(wp + ((size_t)((nt * 8 + ni) * KST + ks) * 64 + lane) * 8);
#pragma unroll
      for (int mi = 0; mi < 4; ++mi)
        acc[mi][ni] = __builtin_amdgcn_mfma_f32_16x16x32_f16(af[mi], bfr, acc[mi][ni], 0, 0, 0);
    }
  }
}

__device__ __forceinline__ void store_relu(const f32x4 acc[4][8], _Float16* __restrict__ dst,
                                           int lane, int mt, int nt) {
#pragma unroll
  for (int mi = 0; mi < 4; ++mi) {
    const int r0 = mt * 64 + mi * 16 + (lane >> 4) * 4;
#pragma unroll
    for (int ni = 0; ni < 8; ++ni) {
      const int n = nt * 128 + ni * 16 + (lane & 15);
#pragma unroll
      for (int ii = 0; ii < 4; ++ii)
        dst[(r0 + ii) * ASTRIDE + n] = (_Float16)fmaxf(acc[mi][ni][ii], 0.0f);
    }
  }
}

__global__ __launch_bounds__(256, 1) void mlp_fw(
    const _Float16* __restrict__ apack, const float* __restrict__ cosin_buf,
    const _Float16* __restrict__ wp,
    const float* __restrict__ b0, const float* __restrict__ b1,
    const float* __restrict__ b2, const float* __restrict__ b3,
    const float* __restrict__ b4, const float* __restrict__ b5,
    const float* __restrict__ b6, const float* __restrict__ b7,
    const float* __restrict__ wl, const float* __restrict__ bl,
    float* __restrict__ out) {
  extern __shared__ _Float16 smem[];
  _Float16* A0 = smem;
  _Float16* A1 = smem + 128 * ASTRIDE;
  const int tid = threadIdx.x, wave = tid >> 6, lane = tid & 63;
  const int mt = wave >> 1, nt = wave & 1;
  const int rtb = blockIdx.x * 8 + mt * 4;

  f32x4 acc[4][8];

  init_bias(acc, b0, lane, nt);
  gemm_glob<3, 0, 3>(acc, apack, wp + OB0, lane, mt, nt, rtb);
  store_relu(acc, A0, lane, mt, nt); __syncthreads();

  init_bias(acc, b1, lane, nt);
  gemm_lds<8, 0, 8>(acc, A0, wp + OB1, lane, mt, nt);
  store_relu(acc, A1, lane, mt, nt); __syncthreads();

  init_bias(acc, b2, lane, nt);
  gemm_lds<8, 0, 8>(acc, A1, wp + OB2, lane, mt, nt);
  store_relu(acc, A0, lane, mt, nt); __syncthreads();

  init_bias(acc, b3, lane, nt);
  gemm_lds<8, 0, 8>(acc, A0, wp + OB3, lane, mt, nt);
  store_relu(acc, A1, lane, mt, nt); __syncthreads();

  init_bias(acc, b4, lane, nt);
  gemm_lds<8, 0, 8>(acc, A1, wp + OB4, lane, mt, nt);
  store_relu(acc, A0, lane, mt, nt); __syncthreads();

  init_bias(acc, b5, lane, nt);
  gemm_glob<11, 0, 3>(acc, apack, wp + OB5, lane, mt, nt, rtb);   // alpha part of concat
  gemm_lds<11, 3, 11>(acc, A0, wp + OB5, lane, mt, nt);           // h part
  store_relu(acc, A1, lane, mt, nt); __syncthreads();

  init_bias(acc, b6, lane, nt);
  gemm_lds<8, 0, 8>(acc, A1, wp + OB6, lane, mt, nt);
  store_relu(acc, A0, lane, mt, nt); __syncthreads();

  init_bias(acc, b7, lane, nt);
  gemm_lds<8, 0, 8>(acc, A0, wp + OB7, lane, mt, nt);
  store_relu(acc, A1, lane, mt, nt); __syncthreads();

  // final: dot(h, w_last) + b_last -> sigmoid -> * cosin
  if (tid < 128) {
    float p = bl[0];
#pragma unroll
    for (int kk = 0; kk < 32; ++kk) {
      const half8 h8 = *(const half8*)(A1 + tid * ASTRIDE + kk * 8);
#pragma unroll
      for (int jj = 0; jj < 8; ++jj) p += (float)h8[jj] * wl[kk * 8 + jj];
    }
    const int ray = blockIdx.x * 128 + tid;
    const float vv = 1.0f / (1.0f + __expf(-p));
    out[ray] = vv * cosin_buf[ray];
  }
}

// ================= launch =================
extern "C" void kernel_launch(void* const* d_in, const int* in_sizes, int n_in,
                              void* d_out, int out_size, void* d_ws, size_t ws_size,
                              hipStream_t stream) {
  const float* pts    = (const float*)d_in[0];
  const float* lights = (const float*)d_in[1];
  const float* sincol = (const float*)d_in[2];
  const float* normal = (const float*)d_in[3];
  const float* rb     = (const float*)d_in[4];
  const float* wf     = (const float*)d_in[5];
  const float* bf     = (const float*)d_in[6];
  const float* wlast  = (const float*)d_in[7];
  const float* blast  = (const float*)d_in[8];
  const float* w0 = (const float*)d_in[9];  const float* b0 = (const float*)d_in[10];
  const float* w1 = (const float*)d_in[11]; const float* b1 = (const float*)d_in[12];
  const float* w2 = (const float*)d_in[13]; const float* b2 = (const float*)d_in[14];
  const float* w3 = (const float*)d_in[15]; const float* b3 = (const float*)d_in[16];
  const float* w4 = (const float*)d_in[17]; const float* b4 = (const float*)d_in[18];
  const float* w5 = (const float*)d_in[19]; const float* b5 = (const float*)d_in[20];
  const float* w6 = (const float*)d_in[21]; const float* b6 = (const float*)d_in[22];
  const float* w7 = (const float*)d_in[23]; const float* b7 = (const float*)d_in[24];

  char* ws = (char*)d_ws;
  _Float16* apack = (_Float16*)ws;                              // NRAY*96 f16 = 9.83 MB
  float* cosin_buf = (float*)(ws + (size_t)NRAY * 96 * 2);      // NRAY f32
  _Float16* wpack = (_Float16*)(ws + (size_t)NRAY * 96 * 2 + (size_t)NRAY * 4);
  float* out = (float*)d_out;

  hipFuncSetAttribute((const void*)mlp_fw, hipFuncAttributeMaxDynamicSharedMemorySize,
                      2 * 128 * ASTRIDE * 2);

  prep_w<<<(WPACK_TOTAL + 255) / 256, 256, 0, stream>>>(w0, w1, w2, w3, w4, w5, w6, w7, wpack);
  phase_a<<<NRAY / 4, 256, 0, stream>>>(pts, lights, sincol, normal, rb, wf, bf,
                                        apack, cosin_buf);
  mlp_fw<<<NRAY / 128, 256, 2 * 128 * ASTRIDE * 2, stream>>>(
      apack, cosin_buf, wpack, b0, b1, b2, b3, b4, b5, b6, b7, wlast, blast, out);
}

// Round 3
// 203.132 us; speedup vs baseline: 5.2925x; 1.3128x over previous
//
#include <hip/hip_runtime.h>
#include <math.h>

#define NPTS   512
#define NLIGHT 100
#define NRAY   (NPTS * NLIGHT)   // 51200
#define NS     50
#define NI     30
#define NF     80                // NS + NI
#define HID    256
#define NEAR_  0.1f
#define FAR_   3.0f

typedef _Float16 half8 __attribute__((ext_vector_type(8)));
typedef float    f32x4 __attribute__((ext_vector_type(4)));

// ---- packed weight layout (f16 elements), B-fragment major ----
// per layer: idx = ((nf*KST + ks)*64 + lane)*8 + j ; n = nf*16 + (lane&15),
// k = ks*32 + ((lane>>4)&3)*8 + j
#define KP0 96
#define KP5 352
#define OB0 0
#define OB1 (OB0 + KP0*HID)        // 24576
#define OB2 (OB1 + HID*HID)        // 90112
#define OB3 (OB2 + HID*HID)
#define OB4 (OB3 + HID*HID)
#define OB5 (OB4 + HID*HID)
#define OB6 (OB5 + KP5*HID)
#define OB7 (OB6 + HID*HID)
#define WPACK_TOTAL (OB7 + HID*HID)  // 507904 f16

#define ASTRIDE 264                 // 256 + 8 f16 pad (528B row: bank-stagger)
#define LDS_BYTES (128 * ASTRIDE * 2)   // 67584 B -> 2 blocks/CU

// ================= weight prep: fp32 [K][N] -> packed f16 fragments =================
template <int KST>
__device__ __forceinline__ void decode_kn(int rem, int& n, int& kk) {
  const int j = rem & 7, q = rem >> 3;
  const int lane = q & 63, q2 = q >> 6;
  const int ks = q2 % KST, nf = q2 / KST;
  n  = nf * 16 + (lane & 15);
  kk = ks * 32 + ((lane >> 4) & 3) * 8 + j;
}

__global__ __launch_bounds__(256) void prep_w(
    const float* __restrict__ w0, const float* __restrict__ w1,
    const float* __restrict__ w2, const float* __restrict__ w3,
    const float* __restrict__ w4, const float* __restrict__ w5,
    const float* __restrict__ w6, const float* __restrict__ w7,
    _Float16* __restrict__ wp) {
  const int t = blockIdx.x * 256 + threadIdx.x;
  if (t >= WPACK_TOTAL) return;
  int n, kk;
  float v = 0.0f;
  if (t < OB1)      { decode_kn<3>(t - OB0, n, kk); if (kk < 80) v = w0[kk * HID + n]; }
  else if (t < OB2) { decode_kn<8>(t - OB1, n, kk); v = w1[kk * HID + n]; }
  else if (t < OB3) { decode_kn<8>(t - OB2, n, kk); v = w2[kk * HID + n]; }
  else if (t < OB4) { decode_kn<8>(t - OB3, n, kk); v = w3[kk * HID + n]; }
  else if (t < OB5) { decode_kn<8>(t - OB4, n, kk); v = w4[kk * HID + n]; }
  else if (t < OB6) { decode_kn<11>(t - OB5, n, kk);
                      if (kk < 80) v = w5[kk * HID + n];
                      else if (kk >= 96) v = w5[(kk - 16) * HID + n]; }
  else if (t < OB7) { decode_kn<8>(t - OB6, n, kk); v = w6[kk * HID + n]; }
  else              { decode_kn<8>(t - OB7, n, kk); v = w7[kk * HID + n]; }
  wp[t] = (_Float16)v;
}

// ================= Phase A =================
struct RayScratch {
  float zv[NS];
  float cdf[NS - 1];
  float zs[NI];
  float zall[NF];
  float af[NF];
};

__device__ __forceinline__ float sigma_fast(float x, float y, float z,
                                            const float* __restrict__ wfr, float bf0) {
  float s = bf0 + wfr[0] * x + wfr[1] * y + wfr[2] * z;
  float sx, cx, sy, cy, sz, cz;
  __sincosf(x, &sx, &cx);
  __sincosf(y, &sy, &cy);
  __sincosf(z, &sz, &cz);
#pragma unroll
  for (int k = 0; k < 4; ++k) {
    s += wfr[3 + 6 * k + 0] * sx + wfr[3 + 6 * k + 1] * sy + wfr[3 + 6 * k + 2] * sz;
    s += wfr[3 + 6 * k + 3] * cx + wfr[3 + 6 * k + 4] * cy + wfr[3 + 6 * k + 5] * cz;
    if (k < 3) {
      const float sx2 = 2.0f * sx * cx, cx2 = 1.0f - 2.0f * sx * sx;
      const float sy2 = 2.0f * sy * cy, cy2 = 1.0f - 2.0f * sy * sy;
      const float sz2 = 2.0f * sz * cz, cz2 = 1.0f - 2.0f * sz * sz;
      sx = sx2; cx = cx2; sy = sy2; cy = cy2; sz = sz2; cz = cz2;
    }
  }
  return s;
}

__global__ __launch_bounds__(256) void phase_a(
    const float* __restrict__ pts, const float* __restrict__ lights,
    const float* __restrict__ sincol, const float* __restrict__ normal,
    const float* __restrict__ rb, const float* __restrict__ wf,
    const float* __restrict__ bf,
    _Float16* __restrict__ apack, float* __restrict__ cosin_out) {
  __shared__ RayScratch sh[4];
  const int wave = threadIdx.x >> 6;
  const int lane = threadIdx.x & 63;
  const int ray  = blockIdx.x * 4 + wave;
  const int i = ray / NLIGHT, j = ray % NLIGHT;
  RayScratch& S = sh[wave];

  float wfr[27];
#pragma unroll
  for (int k = 0; k < 27; ++k) wfr[k] = wf[k];
  const float bf0 = bf[0];

  const float px = pts[3 * i + 0], py = pts[3 * i + 1], pz = pts[3 * i + 2];
  const float dx = lights[3 * j + 0] - px;
  const float dy = lights[3 * j + 1] - py;
  const float dz = lights[3 * j + 2] - pz;
  const float nrm = sqrtf(dx * dx + dy * dy + dz * dz);
  const float rdx = dx / nrm, rdy = dy / nrm, rdz = dz / nrm;
  const float n2 = sqrtf(rdx * rdx + rdy * rdy + rdz * rdz);

  if (lane == 0) {
    const float dotn = rdx * normal[3 * i + 0] + rdy * normal[3 * i + 1] + rdz * normal[3 * i + 2];
    cosin_out[ray] = (dotn > 0.0f) ? 1.0f : 0.0f;
  }

  if (lane < NS) {
    const float t = (float)lane / (float)(NS - 1);
    S.zv[lane] = NEAR_ * (1.0f - t) + FAR_ * t;
  }
  __syncthreads();

  // coarse alpha (lane-local)
  float a = 0.0f;
  if (lane < NS) {
    const float z = S.zv[lane];
    const float bias = (sincol[j] * z * 0.01f) * (rb[(i * NLIGHT + j) * NS + lane] * 2.0f - 1.0f);
    const float sig = sigma_fast(px + rdx * z + bias, py + rdy * z + bias, pz + rdz * z + bias, wfr, bf0);
    const float dist = (lane < NS - 1) ? (S.zv[lane + 1] - z) : 1e10f;
    a = 1.0f - __expf(-fmaxf(sig, 0.0f) * dist);
  }

  // parallel exclusive product scan for transmittance
  float v = (lane < NS) ? (1.0f - a + 1e-10f) : 1.0f;
#pragma unroll
  for (int off = 1; off < 64; off <<= 1) {
    const float o = __shfl_up(v, off, 64);
    if (lane >= off) v *= o;
  }
  float trans = __shfl_up(v, 1, 64);
  if (lane == 0) trans = 1.0f;
  const float w = a * trans;
  const float ww = (lane >= 1 && lane <= NS - 2) ? (w + 1e-5f) : 0.0f;
  // wave sum
  float t = ww;
#pragma unroll
  for (int off = 1; off < 64; off <<= 1) t += __shfl_xor(t, off, 64);
  const float pdf = ww / t;
  // inclusive sum scan of pdf -> cdf
  float c = pdf;
#pragma unroll
  for (int off = 1; off < 64; off <<= 1) {
    const float o = __shfl_up(c, off, 64);
    if (lane >= off) c += o;
  }
  if (lane < NS - 1) S.cdf[lane] = c;  // lane0 holds 0
  __syncthreads();

  if (lane < NI) {
    const float u = (float)lane / (float)(NI - 1);
    int ind = 0;
#pragma unroll
    for (int k = 0; k < NS - 1; ++k)
      if (S.cdf[k] <= u) ind = k + 1;
    const int below = max(ind - 1, 0);
    const int above = min(ind, NS - 2);
    const float c0 = S.cdf[below], c1 = S.cdf[above];
    const float b0v = 0.5f * (S.zv[below] + S.zv[below + 1]);
    const float b1v = 0.5f * (S.zv[above] + S.zv[above + 1]);
    float den = c1 - c0;
    if (den < 1e-5f) den = 1.0f;
    S.zs[lane] = b0v + (u - c0) / den * (b1v - b0v);
  }
  __syncthreads();

  // parallel rank merge (stable: zv before zs on ties)
  if (lane < NS) {
    const float zvv = S.zv[lane];
    int cnt = 0;
#pragma unroll
    for (int k = 0; k < NI; ++k) cnt += (S.zs[k] < zvv) ? 1 : 0;
    S.zall[lane + cnt] = zvv;
  }
  __syncthreads();
  if (lane < NI) {
    const float zsv = S.zs[lane];
    int cnt = 0;
#pragma unroll
    for (int k = 0; k < NS; ++k) cnt += (S.zv[k] <= zsv) ? 1 : 0;
    S.zall[lane + cnt] = zsv;
  }
  __syncthreads();

  for (int k = lane; k < NF; k += 64) {
    const float z = S.zall[k];
    const float d = ((k < NF - 1) ? (S.zall[k + 1] - z) : 1e10f) * n2;
    const float sig = sigma_fast(px + rdx * z, py + rdy * z, pz + rdz * z, wfr, bf0);
    S.af[k] = 1.0f - __expf(-fmaxf(sig, 0.0f) * d);
  }
  __syncthreads();

  // pack alpha into A-fragment layout (padded to K=96 with zeros)
  if (lane < 12) {
    const int ks = lane >> 2, kb = lane & 3;
    half8 vv;
#pragma unroll
    for (int jj = 0; jj < 8; ++jj) {
      const int k = ks * 32 + kb * 8 + jj;
      vv[jj] = (_Float16)((k < NF) ? S.af[k] : 0.0f);
    }
    *(half8*)(apack + ((size_t)((ray >> 4) * 3 + ks) * 64 + kb * 16 + (ray & 15)) * 8) = vv;
  }
}

// ================= Phase B: f16 MFMA MLP =================
// block: 256 thr = 4 waves, 128 rays. wave (mt,nt): rays [mt*64,+64), neurons [nt*128,+128).
// acc[4][8] 16x16 fragments. Single A buffer [128][ASTRIDE] f16 (67.6KB -> 2 blocks/CU).
// Per layer: gemm (LDS reads interleaved with MFMA) ; barrier ; store ; barrier.

__device__ __forceinline__ void init_bias(f32x4 acc[4][8], const float* __restrict__ b,
                                          int lane, int nt) {
#pragma unroll
  for (int ni = 0; ni < 8; ++ni) {
    const float bv = b[nt * 128 + ni * 16 + (lane & 15)];
#pragma unroll
    for (int mi = 0; mi < 4; ++mi) {
      acc[mi][ni][0] = bv; acc[mi][ni][1] = bv; acc[mi][ni][2] = bv; acc[mi][ni][3] = bv;
    }
  }
}

template <int KST, int KS0, int KSN>
__device__ __forceinline__ void gemm_lds(f32x4 acc[4][8], const _Float16* __restrict__ src,
                                         const _Float16* __restrict__ wp, int lane, int mt, int nt) {
#pragma unroll
  for (int ks = KS0; ks < KSN; ++ks) {
    half8 af[4];
    const int kb = (ks - KS0) * 32 + (lane >> 4) * 8;
#pragma unroll
    for (int mi = 0; mi < 4; ++mi) {
      const int row = mt * 64 + mi * 16 + (lane & 15);
      af[mi] = *(const half8*)(src + row * ASTRIDE + kb);
    }
#pragma unroll
    for (int ni = 0; ni < 8; ++ni) {
      const half8 bfr = *(const half8*)(wp + ((size_t)((nt * 8 + ni) * KST + ks) * 64 + lane) * 8);
#pragma unroll
      for (int mi = 0; mi < 4; ++mi)
        acc[mi][ni] = __builtin_amdgcn_mfma_f32_16x16x32_f16(af[mi], bfr, acc[mi][ni], 0, 0, 0);
    }
  }
}

template <int KST, int KS0, int KSN>
__device__ __forceinline__ void gemm_glob(f32x4 acc[4][8], const _Float16* __restrict__ ap,
                                          const _Float16* __restrict__ wp, int lane, int mt, int nt,
                                          int rtb) {
#pragma unroll
  for (int ks = KS0; ks < KSN; ++ks) {
    half8 af[4];
#pragma unroll
    for (int mi = 0; mi < 4; ++mi)
      af[mi] = *(const half8*)(ap + ((size_t)((rtb + mi) * 3 + (ks - KS0)) * 64 + lane) * 8);
#pragma unroll
    for (int ni = 0; ni < 8; ++ni) {
      const half8 bfr = *(const half8*)(wp + ((size_t)((nt * 8 + ni) * KST + ks) * 64 + lane) * 8);
#pragma unroll
      for (int mi = 0; mi < 4; ++mi)
        acc[mi][ni] = __builtin_amdgcn_mfma_f32_16x16x32_f16(af[mi], bfr, acc[mi][ni], 0, 0, 0);
    }
  }
}

__device__ __forceinline__ void store_relu(const f32x4 acc[4][8], _Float16* __restrict__ dst,
                                           int lane, int mt, int nt) {
#pragma unroll
  for (int mi = 0; mi < 4; ++mi) {
    const int r0 = mt * 64 + mi * 16 + (lane >> 4) * 4;
#pragma unroll
    for (int ni = 0; ni < 8; ++ni) {
      const int n = nt * 128 + ni * 16 + (lane & 15);
#pragma unroll
      for (int ii = 0; ii < 4; ++ii)
        dst[(r0 + ii) * ASTRIDE + n] = (_Float16)fmaxf(acc[mi][ni][ii], 0.0f);
    }
  }
}

__global__ __launch_bounds__(256, 2) void mlp_fw(
    const _Float16* __restrict__ apack, const float* __restrict__ cosin_buf,
    const _Float16* __restrict__ wp,
    const float* __restrict__ b0, const float* __restrict__ b1,
    const float* __restrict__ b2, const float* __restrict__ b3,
    const float* __restrict__ b4, const float* __restrict__ b5,
    const float* __restrict__ b6, const float* __restrict__ b7,
    const float* __restrict__ wl, const float* __restrict__ bl,
    float* __restrict__ out) {
  extern __shared__ _Float16 A[];   // [128][ASTRIDE]
  const int tid = threadIdx.x, wave = tid >> 6, lane = tid & 63;
  const int mt = wave >> 1, nt = wave & 1;
  const int rtb = blockIdx.x * 8 + mt * 4;

  f32x4 acc[4][8];

  // layer 0 (A from global apack)
  init_bias(acc, b0, lane, nt);
  gemm_glob<3, 0, 3>(acc, apack, wp + OB0, lane, mt, nt, rtb);
  store_relu(acc, A, lane, mt, nt); __syncthreads();

  // layers 1..4
  init_bias(acc, b1, lane, nt);
  gemm_lds<8, 0, 8>(acc, A, wp + OB1, lane, mt, nt); __syncthreads();
  store_relu(acc, A, lane, mt, nt); __syncthreads();

  init_bias(acc, b2, lane, nt);
  gemm_lds<8, 0, 8>(acc, A, wp + OB2, lane, mt, nt); __syncthreads();
  store_relu(acc, A, lane, mt, nt); __syncthreads();

  init_bias(acc, b3, lane, nt);
  gemm_lds<8, 0, 8>(acc, A, wp + OB3, lane, mt, nt); __syncthreads();
  store_relu(acc, A, lane, mt, nt); __syncthreads();

  init_bias(acc, b4, lane, nt);
  gemm_lds<8, 0, 8>(acc, A, wp + OB4, lane, mt, nt); __syncthreads();
  store_relu(acc, A, lane, mt, nt); __syncthreads();

  // layer 5: concat [alpha(96 pad) | h(256)]
  init_bias(acc, b5, lane, nt);
  gemm_glob<11, 0, 3>(acc, apack, wp + OB5, lane, mt, nt, rtb);
  gemm_lds<11, 3, 11>(acc, A, wp + OB5, lane, mt, nt); __syncthreads();
  store_relu(acc, A, lane, mt, nt); __syncthreads();

  // layers 6,7
  init_bias(acc, b6, lane, nt);
  gemm_lds<8, 0, 8>(acc, A, wp + OB6, lane, mt, nt); __syncthreads();
  store_relu(acc, A, lane, mt, nt); __syncthreads();

  init_bias(acc, b7, lane, nt);
  gemm_lds<8, 0, 8>(acc, A, wp + OB7, lane, mt, nt); __syncthreads();
  store_relu(acc, A, lane, mt, nt); __syncthreads();

  // final: dot(h, w_last) + b_last -> sigmoid -> * cosin
  if (tid < 128) {
    float p = bl[0];
#pragma unroll
    for (int kk = 0; kk < 32; ++kk) {
      const half8 h8 = *(const half8*)(A + tid * ASTRIDE + kk * 8);
#pragma unroll
      for (int jj = 0; jj < 8; ++jj) p += (float)h8[jj] * wl[kk * 8 + jj];
    }
    const int ray = blockIdx.x * 128 + tid;
    const float vv = 1.0f / (1.0f + __expf(-p));
    out[ray] = vv * cosin_buf[ray];
  }
}

// ================= launch =================
extern "C" void kernel_launch(void* const* d_in, const int* in_sizes, int n_in,
                              void* d_out, int out_size, void* d_ws, size_t ws_size,
                              hipStream_t stream) {
  const float* pts    = (const float*)d_in[0];
  const float* lights = (const float*)d_in[1];
  const float* sincol = (const float*)d_in[2];
  const float* normal = (const float*)d_in[3];
  const float* rb     = (const float*)d_in[4];
  const float* wf     = (const float*)d_in[5];
  const float* bf     = (const float*)d_in[6];
  const float* wlast  = (const float*)d_in[7];
  const float* blast  = (const float*)d_in[8];
  const float* w0 = (const float*)d_in[9];  const float* b0 = (const float*)d_in[10];
  const float* w1 = (const float*)d_in[11]; const float* b1 = (const float*)d_in[12];
  const float* w2 = (const float*)d_in[13]; const float* b2 = (const float*)d_in[14];
  const float* w3 = (const float*)d_in[15]; const float* b3 = (const float*)d_in[16];
  const float* w4 = (const float*)d_in[17]; const float* b4 = (const float*)d_in[18];
  const float* w5 = (const float*)d_in[19]; const float* b5 = (const float*)d_in[20];
  const float* w6 = (const float*)d_in[21]; const float* b6 = (const float*)d_in[22];
  const float* w7 = (const float*)d_in[23]; const float* b7 = (const float*)d_in[24];

  char* ws = (char*)d_ws;
  _Float16* apack = (_Float16*)ws;                              // NRAY*96 f16 = 9.83 MB
  float* cosin_buf = (float*)(ws + (size_t)NRAY * 96 * 2);      // NRAY f32
  _Float16* wpack = (_Float16*)(ws + (size_t)NRAY * 96 * 2 + (size_t)NRAY * 4);
  float* out = (float*)d_out;

  hipFuncSetAttribute((const void*)mlp_fw, hipFuncAttributeMaxDynamicSharedMemorySize,
                      LDS_BYTES);

  prep_w<<<(WPACK_TOTAL + 255) / 256, 256, 0, stream>>>(w0, w1, w2, w3, w4, w5, w6, w7, wpack);
  phase_a<<<NRAY / 4, 256, 0, stream>>>(pts, lights, sincol, normal, rb, wf, bf,
                                        apack, cosin_buf);
  mlp_fw<<<NRAY / 128, 256, LDS_BYTES, stream>>>(
      apack, cosin_buf, wpack, b0, b1, b2, b3, b4, b5, b6, b7, wlast, blast, out);
}